// Round 7
// baseline (144.990 us; speedup 1.0000x reference)
//
#include <hip/hip_runtime.h>

typedef __bf16 bf16_t;
typedef __attribute__((ext_vector_type(8))) __bf16 bf16x8;
typedef __attribute__((ext_vector_type(4))) __bf16 bf16x4;
typedef __attribute__((ext_vector_type(2))) __bf16 bf16x2;
typedef __attribute__((ext_vector_type(4))) float f32x4;

#define S_LEN 4096
#define D_MODEL 1024
#define NH 16
#define DKH 64
#define WIN 256
#define NGLOB 16
#define HSZ (S_LEN * DKH)

// async 16B global->LDS copy (dest: wave-uniform base + lane*16)
__device__ inline void g2l16(const void* g, void* l) {
  __builtin_amdgcn_global_load_lds(
      (__attribute__((address_space(1))) void*)(void*)g,
      (__attribute__((address_space(3))) void*)l, 16, 0, 0);
}

// ---------------------------------------------------------------------------
// Shared GEMM body: C[128x128] = A[128,K] * Bt[128,K]^T, bf16 in, f32 acc.
// 4 waves (2x2), each 64x64 via 4x4 of 16x16x32 MFMA, BK=32.
// 2-PHASE DOUBLE-BUFFER (T3 minimum recipe): per K-step t:
//   barrier (drains stage issued at t-1, after a full compute phase)
//   STAGE(t+1 -> buf^1)   (async loads fly during compute below)
//   ds_read buf + 16 MFMA
// One barrier/K-step; vmcnt(0) never drains a freshly-issued load.
// Bank-conflict-free via row-pair XOR swizzle (R6, verified 0 conflicts):
// LDS[mr][t16] holds global 16B-slot (t16 ^ (mr&7)) of macro-row mr (2 rows);
// store side pre-swizzles the GLOBAL source (dest stays linear, rule 21),
// read side applies the same XOR.
// ---------------------------------------------------------------------------
#define GEMM_STAGE(AA, BB, kk0, buf)                                          \
  _Pragma("unroll") for (int i = 0; i < 2; i++) {                             \
    const int c = wave * 2 + i; /* chunk 0..7 (16 rows, 1KB) */               \
    const int row0 = c * 16;                                                  \
    g2l16(AA + (size_t)(m0 + row0 + srow) * D_MODEL + (kk0) + scol,           \
          &As[(buf) * 4096 + c * 512]);                                       \
    g2l16(BB + (size_t)(n0 + row0 + srow) * D_MODEL + (kk0) + scol,           \
          &Bs[(buf) * 4096 + c * 512]);                                       \
  }

#define GEMM_BODY(A, Bt)                                                      \
  __shared__ bf16_t As[2 * 128 * 32];                                         \
  __shared__ bf16_t Bs[2 * 128 * 32];                                         \
  const int tid = threadIdx.x;                                                \
  const int wave = tid >> 6, lane = tid & 63;                                 \
  const int wr = wave >> 1, wc = wave & 1;                                    \
  f32x4 acc[4][4];                                                            \
  _Pragma("unroll") for (int i = 0; i < 4; i++) _Pragma("unroll")             \
      for (int j = 0; j < 4; j++) acc[i][j] = {0.f, 0.f, 0.f, 0.f};          \
  /* staging: lane l -> linear LDS byte 16*l within its 1KB chunk.       */   \
  /* swizzled source: s=(l&7)^(l>>3); row=2*(l>>3)+(s>>2); col=8*(s&3).  */   \
  const int ssl = (lane & 7) ^ (lane >> 3);                                   \
  const int srow = 2 * (lane >> 3) + (ssl >> 2);                              \
  const int scol = 8 * (ssl & 3);                                             \
  const int fr = lane & 15;                                                   \
  const int fkg = lane >> 4; /* 16B k-slot 0..3 */                            \
  int cur = 0;                                                                \
  GEMM_STAGE(A, Bt, 0, 0)                                                     \
  for (int t = 0; t < 32; ++t) {                                              \
    __syncthreads(); /* drains prev stage (latency already hidden) */         \
    if (t + 1 < 32) { GEMM_STAGE(A, Bt, (t + 1) * 32, cur ^ 1) }              \
    bf16x8 af[4], bfr[4];                                                     \
    _Pragma("unroll") for (int m = 0; m < 4; m++) {                           \
      const int rr = wr * 64 + m * 16 + fr;                                   \
      af[m] = *(const bf16x8*)&As[cur * 4096 + (rr >> 1) * 64 +               \
                                  ((((rr & 1) << 2) + fkg) ^ ((rr >> 1) & 7)) \
                                      * 8];                                   \
    }                                                                         \
    _Pragma("unroll") for (int n = 0; n < 4; n++) {                           \
      const int rr = wc * 64 + n * 16 + fr;                                   \
      bfr[n] = *(const bf16x8*)&Bs[cur * 4096 + (rr >> 1) * 64 +              \
                                   ((((rr & 1) << 2) + fkg) ^                 \
                                    ((rr >> 1) & 7)) *                        \
                                       8];                                    \
    }                                                                         \
    _Pragma("unroll") for (int m = 0; m < 4; m++) _Pragma("unroll")           \
        for (int n = 0; n < 4; n++) acc[m][n] =                               \
            __builtin_amdgcn_mfma_f32_16x16x32_bf16(af[m], bfr[n],            \
                                                    acc[m][n], 0, 0, 0);      \
    cur ^= 1;                                                                 \
  }                                                                           \
  const int cr = (lane >> 4) * 4;                                             \
  const int cc = lane & 15;

// ---------------------------------------------------------------------------
// Fused Q/K/V projection, 1-D grid of 768 with chunked XCD swizzle so the 8
// n-blocks sharing an A-panel run on the SAME XCD (A fetched once per panel).
// which=0: Q bf16 [h][s][64] scaled 0.125; 1: K bf16; 2: V^T bf16 [h][64][s].
// ---------------------------------------------------------------------------
__global__ __launch_bounds__(256) void gemm_qkv(
    const bf16_t* __restrict__ Xq, const bf16_t* __restrict__ Xk,
    const bf16_t* __restrict__ Xv, const bf16_t* __restrict__ Wt,
    const float* __restrict__ bq, const float* __restrict__ bk,
    const float* __restrict__ bv, bf16_t* __restrict__ Qo,
    bf16_t* __restrict__ Ko, bf16_t* __restrict__ Vto) {
  const int lin = blockIdx.x;
  const int wg = ((lin & 7) * 96) + (lin >> 3);  // 768 = 8 XCD * 96
  const int n0 = (wg & 7) * 128;
  const int m0 = ((wg >> 3) & 31) * 128;
  const int which = wg >> 8;

  const bf16_t* A = which == 0 ? Xq : which == 1 ? Xk : Xv;
  const bf16_t* Bt = Wt + (size_t)which * (D_MODEL * D_MODEL);
  const float* bias = which == 0 ? bq : which == 1 ? bk : bv;

  GEMM_BODY(A, Bt)

#pragma unroll
  for (int m = 0; m < 4; m++) {
    const int rowg = m0 + wr * 64 + m * 16 + cr;
#pragma unroll
    for (int n = 0; n < 4; n++) {
      const int colg = n0 + wc * 64 + n * 16 + cc;
      const float bv_ = bias[colg];
      const int h = colg >> 6, d = colg & 63;
#pragma unroll
      for (int r = 0; r < 4; r++) {
        const int s = rowg + r;
        const float v = acc[m][n][r] + bv_;
        if (which == 0)
          Qo[h * HSZ + s * DKH + d] = (bf16_t)(v * 0.125f);
        else if (which == 1)
          Ko[h * HSZ + s * DKH + d] = (bf16_t)v;
        else
          Vto[h * HSZ + d * S_LEN + s] = (bf16_t)v;
      }
    }
  }
}

// Final output projection: f32 out with bias. 256 blocks, same XCD chunking.
__global__ __launch_bounds__(256) void gemm_out(const bf16_t* __restrict__ A_,
                                                const bf16_t* __restrict__ Bt_,
                                                const float* __restrict__ bias,
                                                float* __restrict__ Cout) {
  const int lin = blockIdx.x;
  const int wg = ((lin & 7) * 32) + (lin >> 3);  // 256 = 8 XCD * 32
  const int n0 = (wg & 7) * 128;
  const int m0 = (wg >> 3) * 128;
  GEMM_BODY(A_, Bt_)
#pragma unroll
  for (int m = 0; m < 4; m++) {
    const int rowg = m0 + wr * 64 + m * 16 + cr;
#pragma unroll
    for (int n = 0; n < 4; n++) {
      const int colg = n0 + wc * 64 + n * 16 + cc;
      const float bv_ = bias[colg];
#pragma unroll
      for (int r = 0; r < 4; r++)
        Cout[(size_t)(rowg + r) * D_MODEL + colg] = acc[m][n][r] + bv_;
    }
  }
}

// f32 -> bf16 for the 3 inputs in one launch (grid.x MUST be 4096).
__global__ void convx3(const float* __restrict__ q, const float* __restrict__ k,
                       const float* __restrict__ v, bf16_t* __restrict__ oq,
                       bf16_t* __restrict__ ok, bf16_t* __restrict__ ov) {
  const float* in = blockIdx.y == 0 ? q : blockIdx.y == 1 ? k : v;
  bf16_t* out = blockIdx.y == 0 ? oq : blockIdx.y == 1 ? ok : ov;
  const int i = (blockIdx.x * 256 + threadIdx.x) * 4;
  const float4 x = *(const float4*)&in[i];
  bf16x4 o = {(bf16_t)x.x, (bf16_t)x.y, (bf16_t)x.z, (bf16_t)x.w};
  *(bf16x4*)&out[i] = o;
}

// transpose+convert 4 weight matrices [K,N] f32 -> [N,K] bf16
__global__ void convw(const float* __restrict__ W0, const float* __restrict__ W1,
                      const float* __restrict__ W2, const float* __restrict__ W3,
                      bf16_t* __restrict__ out) {
  __shared__ float t[64][65];
  const float* W = blockIdx.z == 0 ? W0 : blockIdx.z == 1 ? W1
                  : blockIdx.z == 2 ? W2 : W3;
  bf16_t* Wt = out + (size_t)blockIdx.z * (D_MODEL * D_MODEL);
  const int k0 = blockIdx.y * 64, n0 = blockIdx.x * 64;
  const int tx = threadIdx.x & 63, ty = threadIdx.x >> 6;
#pragma unroll
  for (int i = 0; i < 16; i++) {
    const int r = i * 4 + ty;
    t[r][tx] = W[(size_t)(k0 + r) * D_MODEL + n0 + tx];
  }
  __syncthreads();
#pragma unroll
  for (int i = 0; i < 16; i++) {
    const int r = i * 4 + ty;
    Wt[(size_t)(n0 + r) * D_MODEL + k0 + tx] = (bf16_t)t[tx][r];
  }
}

// ---------------------------------------------------------------------------
// Sparse flash attention, swapped-QK^T form (unchanged from R4 pass).
// ---------------------------------------------------------------------------
__global__ __launch_bounds__(256) void attn_kern(const bf16_t* __restrict__ Q,
                                                 const bf16_t* __restrict__ K,
                                                 const bf16_t* __restrict__ V,
                                                 bf16_t* __restrict__ O) {
  __shared__ bf16_t p_lds[4][16 * 40];  // [wave][q*40 + k], padded
  const int wave = threadIdx.x >> 6, lane = threadIdx.x & 63;
  const int h = blockIdx.y;
  const int q0 = blockIdx.x * 64 + wave * 16;
  const bf16_t* Qh = Q + h * HSZ;
  const bf16_t* Kh = K + h * HSZ;
  const bf16_t* Vh = V + h * HSZ;  // V^T: [64][S]

  const int fr = lane & 15;
  const int fk = (lane >> 4) * 8;
  const int cr = (lane >> 4) * 4;

  const bf16x8 aq0 = *(const bf16x8*)&Qh[(q0 + fr) * DKH + fk];
  const bf16x8 aq1 = *(const bf16x8*)&Qh[(q0 + fr) * DKH + 32 + fk];

  f32x4 acc_o[4];
#pragma unroll
  for (int i = 0; i < 4; i++) acc_o[i] = {0.f, 0.f, 0.f, 0.f};
  float m_run = -1e30f, l_run = 0.f;

  const int kt_end = (q0 + 15) >> 5;
  int kt_lo = (q0 - WIN) >> 5;
  if (kt_lo < 0) kt_lo = 0;
  const int nt = kt_end - kt_lo + 1 + (kt_lo > 0 ? 1 : 0);

#define TILE_KB(t) ((kt_lo > 0) ? ((t) == 0 ? 0 : (kt_lo + (t)-1) * 32) : (t)*32)
#define LOADK(kb, A0, A1, A2, A3)                              \
  A0 = *(const bf16x8*)&Kh[((kb) + fr) * DKH + fk];            \
  A1 = *(const bf16x8*)&Kh[((kb) + fr) * DKH + 32 + fk];       \
  A2 = *(const bf16x8*)&Kh[((kb) + 16 + fr) * DKH + fk];       \
  A3 = *(const bf16x8*)&Kh[((kb) + 16 + fr) * DKH + 32 + fk];

  bf16x8 kc0, kc1, kc2, kc3;
  {
    const int kb0 = TILE_KB(0);
    LOADK(kb0, kc0, kc1, kc2, kc3)
  }

  const int iq = q0 + fr;
  bf16_t* prow = &p_lds[wave][fr * 40];
  const bf16x8* pread = (const bf16x8*)&p_lds[wave][fr * 40 + fk];

  for (int t = 0; t < nt; t++) {
    const int kb = TILE_KB(t);
    bf16x8 kn0, kn1, kn2, kn3;
    const bool have_next = (t + 1 < nt);
    if (have_next) {
      const int nkb = TILE_KB(t + 1);
      LOADK(nkb, kn0, kn1, kn2, kn3)
    }
    bf16x8 vf0 = *(const bf16x8*)&Vh[(0 * 16 + fr) * S_LEN + kb + fk];
    bf16x8 vf1 = *(const bf16x8*)&Vh[(1 * 16 + fr) * S_LEN + kb + fk];
    bf16x8 vf2 = *(const bf16x8*)&Vh[(2 * 16 + fr) * S_LEN + kb + fk];
    bf16x8 vf3 = *(const bf16x8*)&Vh[(3 * 16 + fr) * S_LEN + kb + fk];

    f32x4 s0 = {0.f, 0.f, 0.f, 0.f}, s1 = {0.f, 0.f, 0.f, 0.f};
    s0 = __builtin_amdgcn_mfma_f32_16x16x32_bf16(kc0, aq0, s0, 0, 0, 0);
    s0 = __builtin_amdgcn_mfma_f32_16x16x32_bf16(kc1, aq1, s0, 0, 0, 0);
    s1 = __builtin_amdgcn_mfma_f32_16x16x32_bf16(kc2, aq0, s1, 0, 0, 0);
    s1 = __builtin_amdgcn_mfma_f32_16x16x32_bf16(kc3, aq1, s1, 0, 0, 0);

    float v[8];
#pragma unroll
    for (int r = 0; r < 4; r++) {
      const int j0 = kb + cr + r, j1 = j0 + 16;
      v[r] = (j0 <= iq && (iq - j0 <= WIN || j0 < NGLOB)) ? s0[r] : -1e30f;
      v[4 + r] = (j1 <= iq && (iq - j1 <= WIN || j1 < NGLOB)) ? s1[r] : -1e30f;
    }
    float mt = fmaxf(fmaxf(fmaxf(v[0], v[1]), fmaxf(v[2], v[3])),
                     fmaxf(fmaxf(v[4], v[5]), fmaxf(v[6], v[7])));
    mt = fmaxf(mt, __shfl_xor(mt, 16));
    mt = fmaxf(mt, __shfl_xor(mt, 32));
    const float mn = fmaxf(m_run, mt);
    const float alpha = __expf(m_run - mn);
    m_run = mn;
    float p[8];
    float ps = 0.f;
#pragma unroll
    for (int i = 0; i < 8; i++) {
      p[i] = __expf(v[i] - mn);
      ps += p[i];
    }
    ps += __shfl_xor(ps, 16);
    ps += __shfl_xor(ps, 32);
    l_run = l_run * alpha + ps;

    *(bf16x2*)&prow[cr] = bf16x2{(bf16_t)p[0], (bf16_t)p[1]};
    *(bf16x2*)&prow[cr + 2] = bf16x2{(bf16_t)p[2], (bf16_t)p[3]};
    *(bf16x2*)&prow[16 + cr] = bf16x2{(bf16_t)p[4], (bf16_t)p[5]};
    *(bf16x2*)&prow[16 + cr + 2] = bf16x2{(bf16_t)p[6], (bf16_t)p[7]};

    float alpha_r[4];
#pragma unroll
    for (int r = 0; r < 4; r++) alpha_r[r] = __shfl(alpha, cr + r);

    asm volatile("" ::: "memory");
    const bf16x8 pa = *pread;
    asm volatile("" ::: "memory");

#pragma unroll
    for (int fd = 0; fd < 4; fd++) {
#pragma unroll
      for (int r = 0; r < 4; r++) acc_o[fd][r] *= alpha_r[r];
    }
    acc_o[0] = __builtin_amdgcn_mfma_f32_16x16x32_bf16(pa, vf0, acc_o[0], 0, 0, 0);
    acc_o[1] = __builtin_amdgcn_mfma_f32_16x16x32_bf16(pa, vf1, acc_o[1], 0, 0, 0);
    acc_o[2] = __builtin_amdgcn_mfma_f32_16x16x32_bf16(pa, vf2, acc_o[2], 0, 0, 0);
    acc_o[3] = __builtin_amdgcn_mfma_f32_16x16x32_bf16(pa, vf3, acc_o[3], 0, 0, 0);

    if (have_next) {
      kc0 = kn0; kc1 = kn1; kc2 = kn2; kc3 = kn3;
    }
  }

  const float linv = 1.0f / l_run;
  float inv_r[4];
#pragma unroll
  for (int r = 0; r < 4; r++) inv_r[r] = __shfl(linv, cr + r);

#pragma unroll
  for (int fd = 0; fd < 4; fd++)
#pragma unroll
    for (int r = 0; r < 4; r++) {
      const int s = q0 + cr + r;
      O[(size_t)s * D_MODEL + h * DKH + fd * 16 + fr] =
          (bf16_t)(acc_o[fd][r] * inv_r[r]);
    }
}

extern "C" void kernel_launch(void* const* d_in, const int* in_sizes, int n_in,
                              void* d_out, int out_size, void* d_ws,
                              size_t ws_size, hipStream_t stream) {
  const float* query = (const float*)d_in[0];
  const float* key = (const float*)d_in[1];
  const float* value = (const float*)d_in[2];
  const float* Wq = (const float*)d_in[3];
  const float* bq = (const float*)d_in[4];
  const float* Wk = (const float*)d_in[5];
  const float* bk = (const float*)d_in[6];
  const float* Wv = (const float*)d_in[7];
  const float* bv = (const float*)d_in[8];
  const float* Wo = (const float*)d_in[9];
  const float* bo = (const float*)d_in[10];

  char* ws = (char*)d_ws;
  bf16_t* Qb = (bf16_t*)(ws);                   // 8 MiB [16][4096][64]
  bf16_t* Kb = (bf16_t*)(ws + (8ull << 20));    // 8 MiB
  bf16_t* Vtb = (bf16_t*)(ws + (16ull << 20));  // 8 MiB [16][64][4096]
  bf16_t* Wt = (bf16_t*)(ws + (24ull << 20));   // 4 x 2 MiB (Wq^T..Wo^T)
  bf16_t* Xq = (bf16_t*)(ws + (32ull << 20));   // 8 MiB
  bf16_t* Xk = (bf16_t*)(ws + (40ull << 20));   // 8 MiB
  bf16_t* Xv = (bf16_t*)(ws + (48ull << 20));   // 8 MiB
  bf16_t* Ab = (bf16_t*)(ws + (56ull << 20));   // 8 MiB attn out [4096][1024]

  const size_t WSTRIDE = (size_t)D_MODEL * D_MODEL;

  convw<<<dim3(16, 16, 4), 256, 0, stream>>>(Wq, Wk, Wv, Wo, Wt);
  convx3<<<dim3(4096, 3), 256, 0, stream>>>(query, key, value, Xq, Xk, Xv);

  gemm_qkv<<<768, 256, 0, stream>>>(Xq, Xk, Xv, Wt, bq, bk, bv, Qb, Kb, Vtb);

  attn_kern<<<dim3(64, 16), 256, 0, stream>>>(Qb, Kb, Vtb, Ab);

  gemm_out<<<256, 256, 0, stream>>>(Ab, Wt + 3 * WSTRIDE, bo, (float*)d_out);
}

// Round 8
// 139.635 us; speedup vs baseline: 1.0384x; 1.0384x over previous
//
#include <hip/hip_runtime.h>

typedef __bf16 bf16_t;
typedef __attribute__((ext_vector_type(8))) __bf16 bf16x8;
typedef __attribute__((ext_vector_type(4))) __bf16 bf16x4;
typedef __attribute__((ext_vector_type(2))) __bf16 bf16x2;
typedef __attribute__((ext_vector_type(4))) float f32x4;

#define S_LEN 4096
#define D_MODEL 1024
#define NH 16
#define DKH 64
#define WIN 256
#define NGLOB 16
#define HSZ (S_LEN * DKH)

// async 16B global->LDS copy (dest: wave-uniform base + lane*16)
__device__ inline void g2l16(const void* g, void* l) {
  __builtin_amdgcn_global_load_lds(
      (__attribute__((address_space(1))) void*)(void*)g,
      (__attribute__((address_space(3))) void*)l, 16, 0, 0);
}

// ---------------------------------------------------------------------------
// GEMM tile body: C[BM x 128] = A[BM,1024] * Bt[128,1024]^T, bf16, f32 acc.
// BM=64, BK=32, 4 waves (2x2): wave covers 32x64 = 2x4 frags of 16x16x32.
// 12KB LDS -> 6 blocks/CU for the QKV grid (1536 blocks): TLP covers the
// per-step vmcnt(0)+barrier drain (R7 lesson: explicit dbuf via __syncthreads
// drains just-issued loads; occupancy is the working lever at this tile).
// Bank-conflict-free row-pair XOR swizzle (R6-verified, 0 conflicts):
// store pre-swizzles the GLOBAL source (LDS dest linear, rule 21), read
// applies the same XOR.
// ---------------------------------------------------------------------------
template <int DUMMY>
__device__ __forceinline__ void gemm_body(const bf16_t* __restrict__ A,
                                          const bf16_t* __restrict__ Bt,
                                          int m0, int n0, int wave, int lane,
                                          bf16_t* As, bf16_t* Bs,
                                          f32x4 acc[2][4]) {
  const int wr = wave >> 1, wc = wave & 1;
#pragma unroll
  for (int i = 0; i < 2; i++)
#pragma unroll
    for (int j = 0; j < 4; j++) acc[i][j] = {0.f, 0.f, 0.f, 0.f};
  // staging: chunk = 16 rows x 32 cols (1KB). lane -> linear LDS byte 16*lane.
  // swizzled source: s=(l&7)^(l>>3); row=2*(l>>3)+(s>>2); col=8*(s&3).
  const int ssl = (lane & 7) ^ (lane >> 3);
  const int srow = 2 * (lane >> 3) + (ssl >> 2);
  const int scol = 8 * (ssl & 3);
  const int fr = lane & 15;
  const int fkg = lane >> 4;  // 16B k-slot 0..3

  for (int k0 = 0; k0 < D_MODEL; k0 += 32) {
    {  // A: 4 chunks (64 rows), one per wave
      const int row0 = wave * 16;
      g2l16(A + (size_t)(m0 + row0 + srow) * D_MODEL + k0 + scol,
            &As[wave * 512]);
    }
#pragma unroll
    for (int i = 0; i < 2; i++) {  // B: 8 chunks (128 rows), two per wave
      const int c = wave * 2 + i;
      g2l16(Bt + (size_t)(n0 + c * 16 + srow) * D_MODEL + k0 + scol,
            &Bs[c * 512]);
    }
    __syncthreads();
    bf16x8 af[2], bfr[4];
#pragma unroll
    for (int m = 0; m < 2; m++) {
      const int rr = wr * 32 + m * 16 + fr;
      af[m] = *(const bf16x8*)&As[(rr >> 1) * 64 +
                                  ((((rr & 1) << 2) + fkg) ^ ((rr >> 1) & 7)) *
                                      8];
    }
#pragma unroll
    for (int n = 0; n < 4; n++) {
      const int rr = wc * 64 + n * 16 + fr;
      bfr[n] = *(const bf16x8*)&Bs[(rr >> 1) * 64 +
                                   ((((rr & 1) << 2) + fkg) ^ ((rr >> 1) & 7)) *
                                       8];
    }
#pragma unroll
    for (int m = 0; m < 2; m++)
#pragma unroll
      for (int n = 0; n < 4; n++)
        acc[m][n] = __builtin_amdgcn_mfma_f32_16x16x32_bf16(af[m], bfr[n],
                                                            acc[m][n], 0, 0, 0);
    __syncthreads();
  }
}

// ---------------------------------------------------------------------------
// Fused Q/K/V projection. 1536 blocks (6/CU), XCD-chunked (192/XCD) so the 8
// n-blocks sharing an A-panel run on the same XCD.
// which=0: Q bf16 [h][s][64] scaled 0.125; 1: K bf16; 2: V^T bf16 [h][64][s].
// ---------------------------------------------------------------------------
__global__ __launch_bounds__(256) void gemm_qkv(
    const bf16_t* __restrict__ Xq, const bf16_t* __restrict__ Xk,
    const bf16_t* __restrict__ Xv, const bf16_t* __restrict__ Wt,
    const float* __restrict__ bq, const float* __restrict__ bk,
    const float* __restrict__ bv, bf16_t* __restrict__ Qo,
    bf16_t* __restrict__ Ko, bf16_t* __restrict__ Vto) {
  __shared__ bf16_t As[64 * 32];
  __shared__ bf16_t Bs[128 * 32];
  const int lin = blockIdx.x;
  const int wg = ((lin & 7) * 192) + (lin >> 3);  // 1536 = 8 XCD * 192
  const int n0 = (wg & 7) * 128;
  const int m0 = ((wg >> 3) & 63) * 64;
  const int which = wg >> 9;

  const bf16_t* A = which == 0 ? Xq : which == 1 ? Xk : Xv;
  const bf16_t* Bt = Wt + (size_t)which * (D_MODEL * D_MODEL);
  const float* bias = which == 0 ? bq : which == 1 ? bk : bv;

  const int wave = threadIdx.x >> 6, lane = threadIdx.x & 63;
  f32x4 acc[2][4];
  gemm_body<0>(A, Bt, m0, n0, wave, lane, As, Bs, acc);

  const int wr = wave >> 1, wc = wave & 1;
  const int cr = (lane >> 4) * 4;
  const int cc = lane & 15;
#pragma unroll
  for (int m = 0; m < 2; m++) {
    const int rowg = m0 + wr * 32 + m * 16 + cr;
#pragma unroll
    for (int n = 0; n < 4; n++) {
      const int colg = n0 + wc * 64 + n * 16 + cc;
      const float bv_ = bias[colg];
      const int h = colg >> 6, d = colg & 63;
#pragma unroll
      for (int r = 0; r < 4; r++) {
        const int s = rowg + r;
        const float v = acc[m][n][r] + bv_;
        if (which == 0)
          Qo[h * HSZ + s * DKH + d] = (bf16_t)(v * 0.125f);
        else if (which == 1)
          Ko[h * HSZ + s * DKH + d] = (bf16_t)v;
        else
          Vto[h * HSZ + d * S_LEN + s] = (bf16_t)v;
      }
    }
  }
}

// Final output projection: f32 out with bias. 512 blocks (2/CU), XCD-chunked.
__global__ __launch_bounds__(256) void gemm_out(const bf16_t* __restrict__ A_,
                                                const bf16_t* __restrict__ Bt_,
                                                const float* __restrict__ bias,
                                                float* __restrict__ Cout) {
  __shared__ bf16_t As[64 * 32];
  __shared__ bf16_t Bs[128 * 32];
  const int lin = blockIdx.x;
  const int wg = ((lin & 7) * 64) + (lin >> 3);  // 512 = 8 XCD * 64
  const int n0 = (wg & 7) * 128;
  const int m0 = (wg >> 3) * 64;
  const int wave = threadIdx.x >> 6, lane = threadIdx.x & 63;
  f32x4 acc[2][4];
  gemm_body<0>(A_, Bt_, m0, n0, wave, lane, As, Bs, acc);

  const int wr = wave >> 1, wc = wave & 1;
  const int cr = (lane >> 4) * 4;
  const int cc = lane & 15;
#pragma unroll
  for (int m = 0; m < 2; m++) {
    const int rowg = m0 + wr * 32 + m * 16 + cr;
#pragma unroll
    for (int n = 0; n < 4; n++) {
      const int colg = n0 + wc * 64 + n * 16 + cc;
      const float bv_ = bias[colg];
#pragma unroll
      for (int r = 0; r < 4; r++)
        Cout[(size_t)(rowg + r) * D_MODEL + colg] = acc[m][n][r] + bv_;
    }
  }
}

// f32 -> bf16 for the 3 inputs in one launch (grid.x MUST be 4096).
__global__ void convx3(const float* __restrict__ q, const float* __restrict__ k,
                       const float* __restrict__ v, bf16_t* __restrict__ oq,
                       bf16_t* __restrict__ ok, bf16_t* __restrict__ ov) {
  const float* in = blockIdx.y == 0 ? q : blockIdx.y == 1 ? k : v;
  bf16_t* out = blockIdx.y == 0 ? oq : blockIdx.y == 1 ? ok : ov;
  const int i = (blockIdx.x * 256 + threadIdx.x) * 4;
  const float4 x = *(const float4*)&in[i];
  bf16x4 o = {(bf16_t)x.x, (bf16_t)x.y, (bf16_t)x.z, (bf16_t)x.w};
  *(bf16x4*)&out[i] = o;
}

// transpose+convert 4 weight matrices [K,N] f32 -> [N,K] bf16
__global__ void convw(const float* __restrict__ W0, const float* __restrict__ W1,
                      const float* __restrict__ W2, const float* __restrict__ W3,
                      bf16_t* __restrict__ out) {
  __shared__ float t[64][65];
  const float* W = blockIdx.z == 0 ? W0 : blockIdx.z == 1 ? W1
                  : blockIdx.z == 2 ? W2 : W3;
  bf16_t* Wt = out + (size_t)blockIdx.z * (D_MODEL * D_MODEL);
  const int k0 = blockIdx.y * 64, n0 = blockIdx.x * 64;
  const int tx = threadIdx.x & 63, ty = threadIdx.x >> 6;
#pragma unroll
  for (int i = 0; i < 16; i++) {
    const int r = i * 4 + ty;
    t[r][tx] = W[(size_t)(k0 + r) * D_MODEL + n0 + tx];
  }
  __syncthreads();
#pragma unroll
  for (int i = 0; i < 16; i++) {
    const int r = i * 4 + ty;
    Wt[(size_t)(n0 + r) * D_MODEL + k0 + tx] = (bf16_t)t[tx][r];
  }
}

// ---------------------------------------------------------------------------
// Sparse flash attention, swapped-QK^T form (unchanged from R4 pass).
// ---------------------------------------------------------------------------
__global__ __launch_bounds__(256) void attn_kern(const bf16_t* __restrict__ Q,
                                                 const bf16_t* __restrict__ K,
                                                 const bf16_t* __restrict__ V,
                                                 bf16_t* __restrict__ O) {
  __shared__ bf16_t p_lds[4][16 * 40];  // [wave][q*40 + k], padded
  const int wave = threadIdx.x >> 6, lane = threadIdx.x & 63;
  const int h = blockIdx.y;
  const int q0 = blockIdx.x * 64 + wave * 16;
  const bf16_t* Qh = Q + h * HSZ;
  const bf16_t* Kh = K + h * HSZ;
  const bf16_t* Vh = V + h * HSZ;  // V^T: [64][S]

  const int fr = lane & 15;
  const int fk = (lane >> 4) * 8;
  const int cr = (lane >> 4) * 4;

  const bf16x8 aq0 = *(const bf16x8*)&Qh[(q0 + fr) * DKH + fk];
  const bf16x8 aq1 = *(const bf16x8*)&Qh[(q0 + fr) * DKH + 32 + fk];

  f32x4 acc_o[4];
#pragma unroll
  for (int i = 0; i < 4; i++) acc_o[i] = {0.f, 0.f, 0.f, 0.f};
  float m_run = -1e30f, l_run = 0.f;

  const int kt_end = (q0 + 15) >> 5;
  int kt_lo = (q0 - WIN) >> 5;
  if (kt_lo < 0) kt_lo = 0;
  const int nt = kt_end - kt_lo + 1 + (kt_lo > 0 ? 1 : 0);

#define TILE_KB(t) ((kt_lo > 0) ? ((t) == 0 ? 0 : (kt_lo + (t)-1) * 32) : (t)*32)
#define LOADK(kb, A0, A1, A2, A3)                              \
  A0 = *(const bf16x8*)&Kh[((kb) + fr) * DKH + fk];            \
  A1 = *(const bf16x8*)&Kh[((kb) + fr) * DKH + 32 + fk];       \
  A2 = *(const bf16x8*)&Kh[((kb) + 16 + fr) * DKH + fk];       \
  A3 = *(const bf16x8*)&Kh[((kb) + 16 + fr) * DKH + 32 + fk];

  bf16x8 kc0, kc1, kc2, kc3;
  {
    const int kb0 = TILE_KB(0);
    LOADK(kb0, kc0, kc1, kc2, kc3)
  }

  const int iq = q0 + fr;
  bf16_t* prow = &p_lds[wave][fr * 40];
  const bf16x8* pread = (const bf16x8*)&p_lds[wave][fr * 40 + fk];

  for (int t = 0; t < nt; t++) {
    const int kb = TILE_KB(t);
    bf16x8 kn0, kn1, kn2, kn3;
    const bool have_next = (t + 1 < nt);
    if (have_next) {
      const int nkb = TILE_KB(t + 1);
      LOADK(nkb, kn0, kn1, kn2, kn3)
    }
    bf16x8 vf0 = *(const bf16x8*)&Vh[(0 * 16 + fr) * S_LEN + kb + fk];
    bf16x8 vf1 = *(const bf16x8*)&Vh[(1 * 16 + fr) * S_LEN + kb + fk];
    bf16x8 vf2 = *(const bf16x8*)&Vh[(2 * 16 + fr) * S_LEN + kb + fk];
    bf16x8 vf3 = *(const bf16x8*)&Vh[(3 * 16 + fr) * S_LEN + kb + fk];

    f32x4 s0 = {0.f, 0.f, 0.f, 0.f}, s1 = {0.f, 0.f, 0.f, 0.f};
    s0 = __builtin_amdgcn_mfma_f32_16x16x32_bf16(kc0, aq0, s0, 0, 0, 0);
    s0 = __builtin_amdgcn_mfma_f32_16x16x32_bf16(kc1, aq1, s0, 0, 0, 0);
    s1 = __builtin_amdgcn_mfma_f32_16x16x32_bf16(kc2, aq0, s1, 0, 0, 0);
    s1 = __builtin_amdgcn_mfma_f32_16x16x32_bf16(kc3, aq1, s1, 0, 0, 0);

    float v[8];
#pragma unroll
    for (int r = 0; r < 4; r++) {
      const int j0 = kb + cr + r, j1 = j0 + 16;
      v[r] = (j0 <= iq && (iq - j0 <= WIN || j0 < NGLOB)) ? s0[r] : -1e30f;
      v[4 + r] = (j1 <= iq && (iq - j1 <= WIN || j1 < NGLOB)) ? s1[r] : -1e30f;
    }
    float mt = fmaxf(fmaxf(fmaxf(v[0], v[1]), fmaxf(v[2], v[3])),
                     fmaxf(fmaxf(v[4], v[5]), fmaxf(v[6], v[7])));
    mt = fmaxf(mt, __shfl_xor(mt, 16));
    mt = fmaxf(mt, __shfl_xor(mt, 32));
    const float mn = fmaxf(m_run, mt);
    const float alpha = __expf(m_run - mn);
    m_run = mn;
    float p[8];
    float ps = 0.f;
#pragma unroll
    for (int i = 0; i < 8; i++) {
      p[i] = __expf(v[i] - mn);
      ps += p[i];
    }
    ps += __shfl_xor(ps, 16);
    ps += __shfl_xor(ps, 32);
    l_run = l_run * alpha + ps;

    *(bf16x2*)&prow[cr] = bf16x2{(bf16_t)p[0], (bf16_t)p[1]};
    *(bf16x2*)&prow[cr + 2] = bf16x2{(bf16_t)p[2], (bf16_t)p[3]};
    *(bf16x2*)&prow[16 + cr] = bf16x2{(bf16_t)p[4], (bf16_t)p[5]};
    *(bf16x2*)&prow[16 + cr + 2] = bf16x2{(bf16_t)p[6], (bf16_t)p[7]};

    float alpha_r[4];
#pragma unroll
    for (int r = 0; r < 4; r++) alpha_r[r] = __shfl(alpha, cr + r);

    asm volatile("" ::: "memory");
    const bf16x8 pa = *pread;
    asm volatile("" ::: "memory");

#pragma unroll
    for (int fd = 0; fd < 4; fd++) {
#pragma unroll
      for (int r = 0; r < 4; r++) acc_o[fd][r] *= alpha_r[r];
    }
    acc_o[0] = __builtin_amdgcn_mfma_f32_16x16x32_bf16(pa, vf0, acc_o[0], 0, 0, 0);
    acc_o[1] = __builtin_amdgcn_mfma_f32_16x16x32_bf16(pa, vf1, acc_o[1], 0, 0, 0);
    acc_o[2] = __builtin_amdgcn_mfma_f32_16x16x32_bf16(pa, vf2, acc_o[2], 0, 0, 0);
    acc_o[3] = __builtin_amdgcn_mfma_f32_16x16x32_bf16(pa, vf3, acc_o[3], 0, 0, 0);

    if (have_next) {
      kc0 = kn0; kc1 = kn1; kc2 = kn2; kc3 = kn3;
    }
  }

  const float linv = 1.0f / l_run;
  float inv_r[4];
#pragma unroll
  for (int r = 0; r < 4; r++) inv_r[r] = __shfl(linv, cr + r);

#pragma unroll
  for (int fd = 0; fd < 4; fd++)
#pragma unroll
    for (int r = 0; r < 4; r++) {
      const int s = q0 + cr + r;
      O[(size_t)s * D_MODEL + h * DKH + fd * 16 + fr] =
          (bf16_t)(acc_o[fd][r] * inv_r[r]);
    }
}

extern "C" void kernel_launch(void* const* d_in, const int* in_sizes, int n_in,
                              void* d_out, int out_size, void* d_ws,
                              size_t ws_size, hipStream_t stream) {
  const float* query = (const float*)d_in[0];
  const float* key = (const float*)d_in[1];
  const float* value = (const float*)d_in[2];
  const float* Wq = (const float*)d_in[3];
  const float* bq = (const float*)d_in[4];
  const float* Wk = (const float*)d_in[5];
  const float* bk = (const float*)d_in[6];
  const float* Wv = (const float*)d_in[7];
  const float* bv = (const float*)d_in[8];
  const float* Wo = (const float*)d_in[9];
  const float* bo = (const float*)d_in[10];

  char* ws = (char*)d_ws;
  bf16_t* Qb = (bf16_t*)(ws);                   // 8 MiB [16][4096][64]
  bf16_t* Kb = (bf16_t*)(ws + (8ull << 20));    // 8 MiB
  bf16_t* Vtb = (bf16_t*)(ws + (16ull << 20));  // 8 MiB [16][64][4096]
  bf16_t* Wt = (bf16_t*)(ws + (24ull << 20));   // 4 x 2 MiB (Wq^T..Wo^T)
  bf16_t* Xq = (bf16_t*)(ws + (32ull << 20));   // 8 MiB
  bf16_t* Xk = (bf16_t*)(ws + (40ull << 20));   // 8 MiB
  bf16_t* Xv = (bf16_t*)(ws + (48ull << 20));   // 8 MiB
  bf16_t* Ab = (bf16_t*)(ws + (56ull << 20));   // 8 MiB attn out [4096][1024]

  const size_t WSTRIDE = (size_t)D_MODEL * D_MODEL;

  convw<<<dim3(16, 16, 4), 256, 0, stream>>>(Wq, Wk, Wv, Wo, Wt);
  convx3<<<dim3(4096, 3), 256, 0, stream>>>(query, key, value, Xq, Xk, Xv);

  gemm_qkv<<<1536, 256, 0, stream>>>(Xq, Xk, Xv, Wt, bq, bk, bv, Qb, Kb, Vtb);

  attn_kern<<<dim3(64, 16), 256, 0, stream>>>(Qb, Kb, Vtb, Ab);

  gemm_out<<<512, 256, 0, stream>>>(Ab, Wt + 3 * WSTRIDE, bo, (float*)d_out);
}

// Round 9
// 129.145 us; speedup vs baseline: 1.1227x; 1.0812x over previous
//
#include <hip/hip_runtime.h>

typedef __bf16 bf16_t;
typedef __attribute__((ext_vector_type(8))) __bf16 bf16x8;
typedef __attribute__((ext_vector_type(4))) __bf16 bf16x4;
typedef __attribute__((ext_vector_type(2))) __bf16 bf16x2;
typedef __attribute__((ext_vector_type(4))) float f32x4;

#define S_LEN 4096
#define D_MODEL 1024
#define NH 16
#define DKH 64
#define WIN 256
#define NGLOB 16
#define HSZ (S_LEN * DKH)

// async 16B global->LDS copy (dest: wave-uniform base + lane*16)
__device__ inline void g2l16(const void* g, void* l) {
  __builtin_amdgcn_global_load_lds(
      (__attribute__((address_space(1))) void*)(void*)g,
      (__attribute__((address_space(3))) void*)l, 16, 0, 0);
}

// ---------------------------------------------------------------------------
// Pipelined GEMM body (T3-minimum + T14): C[128x128] = A[128,1024]*Bt[128,1024]^T
// 4 waves (2x2), 4x4 frags of 16x16x32, BK=32, double-buffered LDS (32KB).
// Per K-step: issue A-loads(regs)+B g2l16 for t+1 -> compute t (loads fly
// under MFMA) -> cvt+ds_write A(t+1) -> ONE __syncthreads (its vmcnt(0)
// drains B(t+1), which had the whole compute phase in flight).
// A path: AF32 ? f32 loads + in-reg convert (fuses the convx kernel) : bf16.
// A swizzle on the ds_write DEST; B swizzle on the g2l16 SOURCE (rule 21).
// Swizzle (R6-verified, 0 conflicts): macro-row mr=row>>1 (128B), slot
// t16 = ((row&1)*4+colslot) ^ (mr&7).
// ---------------------------------------------------------------------------
template <bool AF32>
__device__ __forceinline__ void gemm_pipe(const void* __restrict__ Ap,
                                          const bf16_t* __restrict__ Bt,
                                          int m0, int n0, int wave, int lane,
                                          bf16_t* As, bf16_t* Bs,
                                          f32x4 acc[4][4]) {
  const float* Af = (const float*)Ap;
  const bf16_t* Ah = (const bf16_t*)Ap;
  const int wr = wave >> 1, wc = wave & 1;
#pragma unroll
  for (int i = 0; i < 4; i++)
#pragma unroll
    for (int j = 0; j < 4; j++) acc[i][j] = {0.f, 0.f, 0.f, 0.f};

  // A staging (reg->ds_write, swizzled dest): chunk c=wave*2+i (16 rows)
  const int arow_l = lane >> 2;  // 0..15
  const int aslot = lane & 3;    // 16B slot (8 bf16) within 32-col row
  // B staging (g2l16, swizzled source): chunk c (16 rows), linear dest
  const int ssl = (lane & 7) ^ (lane >> 3);
  const int srowB = 2 * (lane >> 3) + (ssl >> 2);
  const int scolB = 8 * (ssl & 3);
  // fragment reads
  const int fr = lane & 15;
  const int fkg = lane >> 4;  // 0..3

#define A_LDS_OFF(c)                                                       \
  ((((c)*16 + arow_l) >> 1) * 64 +                                         \
   (((((c)*16 + arow_l) & 1) << 2 | aslot) ^ ((((c)*16 + arow_l) >> 1) & 7)) * 8)

  // prologue: stage tile 0 -> buf 0
#pragma unroll
  for (int i = 0; i < 2; i++) {
    const int c = wave * 2 + i;
    const int r = c * 16 + arow_l;
    if constexpr (AF32) {
      const float* s = Af + (size_t)(m0 + r) * D_MODEL + aslot * 8;
      const float4 x = *(const float4*)s;
      const float4 y = *(const float4*)(s + 4);
      bf16x8 w = {(bf16_t)x.x, (bf16_t)x.y, (bf16_t)x.z, (bf16_t)x.w,
                  (bf16_t)y.x, (bf16_t)y.y, (bf16_t)y.z, (bf16_t)y.w};
      *(bf16x8*)&As[A_LDS_OFF(c)] = w;
    } else {
      *(bf16x8*)&As[A_LDS_OFF(c)] =
          *(const bf16x8*)(Ah + (size_t)(m0 + r) * D_MODEL + aslot * 8);
    }
    g2l16(Bt + (size_t)(n0 + c * 16 + srowB) * D_MODEL + scolB, &Bs[c * 512]);
  }
  __syncthreads();

#pragma unroll 2
  for (int t = 0; t < 32; ++t) {
    const int buf = t & 1;
    const bool hn = (t < 31);
    float4 ax0{}, ay0{}, ax1{}, ay1{};
    bf16x8 ah0{}, ah1{};
    if (hn) {  // issue next-tile loads: A->regs, B->LDS(buf^1)
      const int kn = (t + 1) * 32;
      {
        const int r0 = (wave * 2) * 16 + arow_l;
        const int r1 = (wave * 2 + 1) * 16 + arow_l;
        if constexpr (AF32) {
          const float* s0 = Af + (size_t)(m0 + r0) * D_MODEL + kn + aslot * 8;
          const float* s1 = Af + (size_t)(m0 + r1) * D_MODEL + kn + aslot * 8;
          ax0 = *(const float4*)s0;
          ay0 = *(const float4*)(s0 + 4);
          ax1 = *(const float4*)s1;
          ay1 = *(const float4*)(s1 + 4);
        } else {
          ah0 = *(const bf16x8*)(Ah + (size_t)(m0 + r0) * D_MODEL + kn + aslot * 8);
          ah1 = *(const bf16x8*)(Ah + (size_t)(m0 + r1) * D_MODEL + kn + aslot * 8);
        }
        g2l16(Bt + (size_t)(n0 + (wave * 2) * 16 + srowB) * D_MODEL + kn + scolB,
              &Bs[(buf ^ 1) * 4096 + (wave * 2) * 512]);
        g2l16(Bt + (size_t)(n0 + (wave * 2 + 1) * 16 + srowB) * D_MODEL + kn + scolB,
              &Bs[(buf ^ 1) * 4096 + (wave * 2 + 1) * 512]);
      }
    }
    __builtin_amdgcn_sched_barrier(0);
    // compute tile t from buf
    bf16x8 af[4], bfr[4];
#pragma unroll
    for (int m = 0; m < 4; m++) {
      const int rr = wr * 64 + m * 16 + fr;
      af[m] = *(const bf16x8*)&As[buf * 4096 + (rr >> 1) * 64 +
                                  ((((rr & 1) << 2) + fkg) ^ ((rr >> 1) & 7)) * 8];
    }
#pragma unroll
    for (int n = 0; n < 4; n++) {
      const int rr = wc * 64 + n * 16 + fr;
      bfr[n] = *(const bf16x8*)&Bs[buf * 4096 + (rr >> 1) * 64 +
                                   ((((rr & 1) << 2) + fkg) ^ ((rr >> 1) & 7)) * 8];
    }
#pragma unroll
    for (int m = 0; m < 4; m++)
#pragma unroll
      for (int n = 0; n < 4; n++)
        acc[m][n] = __builtin_amdgcn_mfma_f32_16x16x32_bf16(af[m], bfr[n],
                                                            acc[m][n], 0, 0, 0);
    __builtin_amdgcn_sched_barrier(0);
    if (hn) {  // write staged A -> LDS(buf^1)
      bf16x8 w0, w1;
      if constexpr (AF32) {
        w0 = bf16x8{(bf16_t)ax0.x, (bf16_t)ax0.y, (bf16_t)ax0.z, (bf16_t)ax0.w,
                    (bf16_t)ay0.x, (bf16_t)ay0.y, (bf16_t)ay0.z, (bf16_t)ay0.w};
        w1 = bf16x8{(bf16_t)ax1.x, (bf16_t)ax1.y, (bf16_t)ax1.z, (bf16_t)ax1.w,
                    (bf16_t)ay1.x, (bf16_t)ay1.y, (bf16_t)ay1.z, (bf16_t)ay1.w};
      } else {
        w0 = ah0;
        w1 = ah1;
      }
      *(bf16x8*)&As[(buf ^ 1) * 4096 + A_LDS_OFF(wave * 2)] = w0;
      *(bf16x8*)&As[(buf ^ 1) * 4096 + A_LDS_OFF(wave * 2 + 1)] = w1;
    }
    __syncthreads();
  }
#undef A_LDS_OFF
}

// ---------------------------------------------------------------------------
// Fused Q/K/V projection reading RAW f32 inputs (convx fused into A-stage).
// 768 blocks XCD-chunked (96/XCD, n-fastest) so the 8 n-blocks sharing an
// A-panel run on the same XCD.
// which=0: Q bf16 [h][s][64] scaled 0.125; 1: K bf16; 2: V^T bf16 [h][64][s].
// ---------------------------------------------------------------------------
__global__ __launch_bounds__(256, 3) void gemm_qkv(
    const float* __restrict__ Xq, const float* __restrict__ Xk,
    const float* __restrict__ Xv, const bf16_t* __restrict__ Wt,
    const float* __restrict__ bq, const float* __restrict__ bk,
    const float* __restrict__ bv, bf16_t* __restrict__ Qo,
    bf16_t* __restrict__ Ko, bf16_t* __restrict__ Vto) {
  __shared__ bf16_t As[2 * 128 * 32];
  __shared__ bf16_t Bs[2 * 128 * 32];
  const int lin = blockIdx.x;
  const int wg = ((lin & 7) * 96) + (lin >> 3);  // 768 = 8 XCD * 96
  const int n0 = (wg & 7) * 128;
  const int m0 = ((wg >> 3) & 31) * 128;
  const int which = wg >> 8;

  const float* A = which == 0 ? Xq : which == 1 ? Xk : Xv;
  const bf16_t* Bt = Wt + (size_t)which * (D_MODEL * D_MODEL);
  const float* bias = which == 0 ? bq : which == 1 ? bk : bv;

  const int wave = threadIdx.x >> 6, lane = threadIdx.x & 63;
  f32x4 acc[4][4];
  gemm_pipe<true>(A, Bt, m0, n0, wave, lane, As, Bs, acc);

  const int wr = wave >> 1, wc = wave & 1;
  const int cr = (lane >> 4) * 4;
  const int cc = lane & 15;
#pragma unroll
  for (int m = 0; m < 4; m++) {
    const int rowg = m0 + wr * 64 + m * 16 + cr;
#pragma unroll
    for (int n = 0; n < 4; n++) {
      const int colg = n0 + wc * 64 + n * 16 + cc;
      const float bv_ = bias[colg];
      const int h = colg >> 6, d = colg & 63;
#pragma unroll
      for (int r = 0; r < 4; r++) {
        const int s = rowg + r;
        const float v = acc[m][n][r] + bv_;
        if (which == 0)
          Qo[h * HSZ + s * DKH + d] = (bf16_t)(v * 0.125f);
        else if (which == 1)
          Ko[h * HSZ + s * DKH + d] = (bf16_t)v;
        else
          Vto[h * HSZ + d * S_LEN + s] = (bf16_t)v;
      }
    }
  }
}

// Final output projection: f32 out with bias. 256 blocks, XCD-chunked.
__global__ __launch_bounds__(256, 3) void gemm_out(
    const bf16_t* __restrict__ A_, const bf16_t* __restrict__ Bt_,
    const float* __restrict__ bias, float* __restrict__ Cout) {
  __shared__ bf16_t As[2 * 128 * 32];
  __shared__ bf16_t Bs[2 * 128 * 32];
  const int lin = blockIdx.x;
  const int wg = ((lin & 7) * 32) + (lin >> 3);  // 256 = 8 XCD * 32
  const int n0 = (wg & 7) * 128;
  const int m0 = (wg >> 3) * 128;
  const int wave = threadIdx.x >> 6, lane = threadIdx.x & 63;
  f32x4 acc[4][4];
  gemm_pipe<false>(A_, Bt_, m0, n0, wave, lane, As, Bs, acc);

  const int wr = wave >> 1, wc = wave & 1;
  const int cr = (lane >> 4) * 4;
  const int cc = lane & 15;
#pragma unroll
  for (int m = 0; m < 4; m++) {
    const int rowg = m0 + wr * 64 + m * 16 + cr;
#pragma unroll
    for (int n = 0; n < 4; n++) {
      const int colg = n0 + wc * 64 + n * 16 + cc;
      const float bv_ = bias[colg];
#pragma unroll
      for (int r = 0; r < 4; r++)
        Cout[(size_t)(rowg + r) * D_MODEL + colg] = acc[m][n][r] + bv_;
    }
  }
}

// transpose+convert 4 weight matrices [K,N] f32 -> [N,K] bf16
__global__ void convw(const float* __restrict__ W0, const float* __restrict__ W1,
                      const float* __restrict__ W2, const float* __restrict__ W3,
                      bf16_t* __restrict__ out) {
  __shared__ float t[64][65];
  const float* W = blockIdx.z == 0 ? W0 : blockIdx.z == 1 ? W1
                  : blockIdx.z == 2 ? W2 : W3;
  bf16_t* Wt = out + (size_t)blockIdx.z * (D_MODEL * D_MODEL);
  const int k0 = blockIdx.y * 64, n0 = blockIdx.x * 64;
  const int tx = threadIdx.x & 63, ty = threadIdx.x >> 6;
#pragma unroll
  for (int i = 0; i < 16; i++) {
    const int r = i * 4 + ty;
    t[r][tx] = W[(size_t)(k0 + r) * D_MODEL + n0 + tx];
  }
  __syncthreads();
#pragma unroll
  for (int i = 0; i < 16; i++) {
    const int r = i * 4 + ty;
    Wt[(size_t)(n0 + r) * D_MODEL + k0 + tx] = (bf16_t)t[tx][r];
  }
}

// ---------------------------------------------------------------------------
// Sparse flash attention, swapped-QK^T form (unchanged from R4 pass).
// ---------------------------------------------------------------------------
__global__ __launch_bounds__(256) void attn_kern(const bf16_t* __restrict__ Q,
                                                 const bf16_t* __restrict__ K,
                                                 const bf16_t* __restrict__ V,
                                                 bf16_t* __restrict__ O) {
  __shared__ bf16_t p_lds[4][16 * 40];  // [wave][q*40 + k], padded
  const int wave = threadIdx.x >> 6, lane = threadIdx.x & 63;
  const int h = blockIdx.y;
  const int q0 = blockIdx.x * 64 + wave * 16;
  const bf16_t* Qh = Q + h * HSZ;
  const bf16_t* Kh = K + h * HSZ;
  const bf16_t* Vh = V + h * HSZ;  // V^T: [64][S]

  const int fr = lane & 15;
  const int fk = (lane >> 4) * 8;
  const int cr = (lane >> 4) * 4;

  const bf16x8 aq0 = *(const bf16x8*)&Qh[(q0 + fr) * DKH + fk];
  const bf16x8 aq1 = *(const bf16x8*)&Qh[(q0 + fr) * DKH + 32 + fk];

  f32x4 acc_o[4];
#pragma unroll
  for (int i = 0; i < 4; i++) acc_o[i] = {0.f, 0.f, 0.f, 0.f};
  float m_run = -1e30f, l_run = 0.f;

  const int kt_end = (q0 + 15) >> 5;
  int kt_lo = (q0 - WIN) >> 5;
  if (kt_lo < 0) kt_lo = 0;
  const int nt = kt_end - kt_lo + 1 + (kt_lo > 0 ? 1 : 0);

#define TILE_KB(t) ((kt_lo > 0) ? ((t) == 0 ? 0 : (kt_lo + (t)-1) * 32) : (t)*32)
#define LOADK(kb, A0, A1, A2, A3)                              \
  A0 = *(const bf16x8*)&Kh[((kb) + fr) * DKH + fk];            \
  A1 = *(const bf16x8*)&Kh[((kb) + fr) * DKH + 32 + fk];       \
  A2 = *(const bf16x8*)&Kh[((kb) + 16 + fr) * DKH + fk];       \
  A3 = *(const bf16x8*)&Kh[((kb) + 16 + fr) * DKH + 32 + fk];

  bf16x8 kc0, kc1, kc2, kc3;
  {
    const int kb0 = TILE_KB(0);
    LOADK(kb0, kc0, kc1, kc2, kc3)
  }

  const int iq = q0 + fr;
  bf16_t* prow = &p_lds[wave][fr * 40];
  const bf16x8* pread = (const bf16x8*)&p_lds[wave][fr * 40 + fk];

  for (int t = 0; t < nt; t++) {
    const int kb = TILE_KB(t);
    bf16x8 kn0, kn1, kn2, kn3;
    const bool have_next = (t + 1 < nt);
    if (have_next) {
      const int nkb = TILE_KB(t + 1);
      LOADK(nkb, kn0, kn1, kn2, kn3)
    }
    bf16x8 vf0 = *(const bf16x8*)&Vh[(0 * 16 + fr) * S_LEN + kb + fk];
    bf16x8 vf1 = *(const bf16x8*)&Vh[(1 * 16 + fr) * S_LEN + kb + fk];
    bf16x8 vf2 = *(const bf16x8*)&Vh[(2 * 16 + fr) * S_LEN + kb + fk];
    bf16x8 vf3 = *(const bf16x8*)&Vh[(3 * 16 + fr) * S_LEN + kb + fk];

    f32x4 s0 = {0.f, 0.f, 0.f, 0.f}, s1 = {0.f, 0.f, 0.f, 0.f};
    s0 = __builtin_amdgcn_mfma_f32_16x16x32_bf16(kc0, aq0, s0, 0, 0, 0);
    s0 = __builtin_amdgcn_mfma_f32_16x16x32_bf16(kc1, aq1, s0, 0, 0, 0);
    s1 = __builtin_amdgcn_mfma_f32_16x16x32_bf16(kc2, aq0, s1, 0, 0, 0);
    s1 = __builtin_amdgcn_mfma_f32_16x16x32_bf16(kc3, aq1, s1, 0, 0, 0);

    float v[8];
#pragma unroll
    for (int r = 0; r < 4; r++) {
      const int j0 = kb + cr + r, j1 = j0 + 16;
      v[r] = (j0 <= iq && (iq - j0 <= WIN || j0 < NGLOB)) ? s0[r] : -1e30f;
      v[4 + r] = (j1 <= iq && (iq - j1 <= WIN || j1 < NGLOB)) ? s1[r] : -1e30f;
    }
    float mt = fmaxf(fmaxf(fmaxf(v[0], v[1]), fmaxf(v[2], v[3])),
                     fmaxf(fmaxf(v[4], v[5]), fmaxf(v[6], v[7])));
    mt = fmaxf(mt, __shfl_xor(mt, 16));
    mt = fmaxf(mt, __shfl_xor(mt, 32));
    const float mn = fmaxf(m_run, mt);
    const float alpha = __expf(m_run - mn);
    m_run = mn;
    float p[8];
    float ps = 0.f;
#pragma unroll
    for (int i = 0; i < 8; i++) {
      p[i] = __expf(v[i] - mn);
      ps += p[i];
    }
    ps += __shfl_xor(ps, 16);
    ps += __shfl_xor(ps, 32);
    l_run = l_run * alpha + ps;

    *(bf16x2*)&prow[cr] = bf16x2{(bf16_t)p[0], (bf16_t)p[1]};
    *(bf16x2*)&prow[cr + 2] = bf16x2{(bf16_t)p[2], (bf16_t)p[3]};
    *(bf16x2*)&prow[16 + cr] = bf16x2{(bf16_t)p[4], (bf16_t)p[5]};
    *(bf16x2*)&prow[16 + cr + 2] = bf16x2{(bf16_t)p[6], (bf16_t)p[7]};

    float alpha_r[4];
#pragma unroll
    for (int r = 0; r < 4; r++) alpha_r[r] = __shfl(alpha, cr + r);

    asm volatile("" ::: "memory");
    const bf16x8 pa = *pread;
    asm volatile("" ::: "memory");

#pragma unroll
    for (int fd = 0; fd < 4; fd++) {
#pragma unroll
      for (int r = 0; r < 4; r++) acc_o[fd][r] *= alpha_r[r];
    }
    acc_o[0] = __builtin_amdgcn_mfma_f32_16x16x32_bf16(pa, vf0, acc_o[0], 0, 0, 0);
    acc_o[1] = __builtin_amdgcn_mfma_f32_16x16x32_bf16(pa, vf1, acc_o[1], 0, 0, 0);
    acc_o[2] = __builtin_amdgcn_mfma_f32_16x16x32_bf16(pa, vf2, acc_o[2], 0, 0, 0);
    acc_o[3] = __builtin_amdgcn_mfma_f32_16x16x32_bf16(pa, vf3, acc_o[3], 0, 0, 0);

    if (have_next) {
      kc0 = kn0; kc1 = kn1; kc2 = kn2; kc3 = kn3;
    }
  }

  const float linv = 1.0f / l_run;
  float inv_r[4];
#pragma unroll
  for (int r = 0; r < 4; r++) inv_r[r] = __shfl(linv, cr + r);

#pragma unroll
  for (int fd = 0; fd < 4; fd++)
#pragma unroll
    for (int r = 0; r < 4; r++) {
      const int s = q0 + cr + r;
      O[(size_t)s * D_MODEL + h * DKH + fd * 16 + fr] =
          (bf16_t)(acc_o[fd][r] * inv_r[r]);
    }
}

extern "C" void kernel_launch(void* const* d_in, const int* in_sizes, int n_in,
                              void* d_out, int out_size, void* d_ws,
                              size_t ws_size, hipStream_t stream) {
  const float* query = (const float*)d_in[0];
  const float* key = (const float*)d_in[1];
  const float* value = (const float*)d_in[2];
  const float* Wq = (const float*)d_in[3];
  const float* bq = (const float*)d_in[4];
  const float* Wk = (const float*)d_in[5];
  const float* bk = (const float*)d_in[6];
  const float* Wv = (const float*)d_in[7];
  const float* bv = (const float*)d_in[8];
  const float* Wo = (const float*)d_in[9];
  const float* bo = (const float*)d_in[10];

  char* ws = (char*)d_ws;
  bf16_t* Qb = (bf16_t*)(ws);                   // 8 MiB [16][4096][64]
  bf16_t* Kb = (bf16_t*)(ws + (8ull << 20));    // 8 MiB
  bf16_t* Vtb = (bf16_t*)(ws + (16ull << 20));  // 8 MiB [16][64][4096]
  bf16_t* Wt = (bf16_t*)(ws + (24ull << 20));   // 4 x 2 MiB (Wq^T..Wo^T)
  bf16_t* Ab = (bf16_t*)(ws + (32ull << 20));   // 8 MiB attn out [4096][1024]

  const size_t WSTRIDE = (size_t)D_MODEL * D_MODEL;

  convw<<<dim3(16, 16, 4), 256, 0, stream>>>(Wq, Wk, Wv, Wo, Wt);

  gemm_qkv<<<768, 256, 0, stream>>>(query, key, value, Wt, bq, bk, bv, Qb, Kb,
                                    Vtb);

  attn_kern<<<dim3(64, 16), 256, 0, stream>>>(Qb, Kb, Vtb, Ab);

  gemm_out<<<256, 256, 0, stream>>>(Ab, Wt + 3 * WSTRIDE, bo, (float*)d_out);
}